// Round 4
// baseline (19.497 us; speedup 1.0000x reference)
//
#include <hip/hip_runtime.h>
#include <hip/hip_bf16.h>

// Co-attention collapses: softmax over a size-1 axis == 1.0 exactly, so
//   out[b, 0:10]  = sum_{l<12}  x1[b, l, :]
//   out[b, 10:20] = sum_{l<100} C [b, l, :]
// Pure memory-bound column-sum. B=16384, LC=100, LS=12, D=10.
//
// R3 post-mortem: occupancy & instruction count are NOT the levers (2x
// occupancy -> -0.5us). Hypothesis: per-wave-load spans were 40 B
// (sub-cache-line) scattered at 4 KB stride -> fragmented request stream,
// ~4.1 TB/s effective vs fills' 6.7 TB/s contiguous.
//
// This round: 4-row group = 160 B = 10 float4. Thread (b, j) loads float4
// slot j of every group (stride 160 B) -> fixed column-phase set
// (4j+i) mod 10 -> static accumulators. 10 consecutive lanes = one
// CONTIGUOUS 160-B span (4x bigger), 16 B/lane. Combine the 10 phase
// threads of a batch via LDS atomicAdd (4 contributions/column), then
// coalesced float2 stores.
// Block = 320 thr (lcm-friendly: 32 batches x 10 slots), grid = 512
// blocks = exactly 2/CU, 10 waves/CU.

#define BATCHES 16384

__global__ __launch_bounds__(320) void coattention_sum_kernel(
    const float4* __restrict__ C4,   // (B, 250) float4
    const float4* __restrict__ x14,  // (B, 30) float4
    float2* __restrict__ out2)       // (B, 10) float2 = (B,20) floats
{
    __shared__ __align__(16) float sums[32 * 20];  // [local_b][20]

    const int t = threadIdx.x;           // 0..319
    // zero the combine buffer
    sums[t] = 0.f;
    sums[t + 320] = 0.f;
    __syncthreads();

    const int bl = t / 10;               // local batch 0..31
    const int j  = t - bl * 10;          // float4 slot in 160-B group, 0..9
    const int b  = blockIdx.x * 32 + bl;

    // C batch = 250 float4 (25 groups of 10); x1 batch = 30 float4 (3 groups)
    const float4* __restrict__ cp = C4 + (size_t)b * 250 + j;
    const float4* __restrict__ xp = x14 + (size_t)b * 30 + j;

    float c0 = 0.f, c1 = 0.f, c2 = 0.f, c3 = 0.f;
#pragma unroll
    for (int g = 0; g < 25; ++g) {
        float4 v = cp[g * 10];
        c0 += v.x; c1 += v.y; c2 += v.z; c3 += v.w;
    }

    float s0 = 0.f, s1 = 0.f, s2 = 0.f, s3 = 0.f;
#pragma unroll
    for (int g = 0; g < 3; ++g) {
        float4 v = xp[g * 10];
        s0 += v.x; s1 += v.y; s2 += v.z; s3 += v.w;
    }

    // this thread's 4 values land in columns (4j+i) mod 10
    const int base = 4 * j;
    const int k0 = base % 10, k1 = (base + 1) % 10;
    const int k2 = (base + 2) % 10, k3 = (base + 3) % 10;

    float* row = &sums[bl * 20];
    atomicAdd(&row[k0], s0);        // sfinal -> out cols 0..9
    atomicAdd(&row[k1], s1);
    atomicAdd(&row[k2], s2);
    atomicAdd(&row[k3], s3);
    atomicAdd(&row[10 + k0], c0);   // cfinal -> out cols 10..19
    atomicAdd(&row[10 + k1], c1);
    atomicAdd(&row[10 + k2], c2);
    atomicAdd(&row[10 + k3], c3);
    __syncthreads();

    // 32 batches x 20 floats = 640 floats = 320 float2, fully coalesced
    out2[(size_t)blockIdx.x * 320 + t] = make_float2(sums[2 * t], sums[2 * t + 1]);
}

extern "C" void kernel_launch(void* const* d_in, const int* in_sizes, int n_in,
                              void* d_out, int out_size, void* d_ws, size_t ws_size,
                              hipStream_t stream) {
    const float4* C4  = (const float4*)d_in[0];   // (B,100,10) = (B,250) float4
    const float4* x14 = (const float4*)d_in[1];   // (B,12,10)  = (B,30)  float4
    float2* out2 = (float2*)d_out;                // (B,1,20)   = (B,10)  float2

    const int grid = BATCHES / 32;                // 512 blocks = 2/CU exactly
    coattention_sum_kernel<<<grid, 320, 0, stream>>>(C4, x14, out2);
}